// Round 4
// baseline (1002.715 us; speedup 1.0000x reference)
//
#include <hip/hip_runtime.h>

#define NN 100000
#define NE 1250000
#define NB 2048

typedef __attribute__((ext_vector_type(8))) short short8;
typedef __attribute__((ext_vector_type(4))) float floatx4;

__device__ inline unsigned short f2bf(float f) {
    unsigned u = __float_as_uint(f);
    u = u + 0x7fffu + ((u >> 16) & 1u);   // RNE
    return (unsigned short)(u >> 16);
}
__device__ inline float bf2f(unsigned short h) {
    return __uint_as_float(((unsigned)h) << 16);
}

// h[n][d] = sum_f atom_emb[f][x_feat[n][f]][d]
__global__ void atom_encode(const float* __restrict__ atom_emb,
                            const int* __restrict__ x_feat,
                            float* __restrict__ h) {
    int id = blockIdx.x * 256 + threadIdx.x;   // N*16 exact
    int n = id >> 4, q = id & 15;
    floatx4 acc = {0.f, 0.f, 0.f, 0.f};
    for (int f = 0; f < 9; f++) {
        int v = x_feat[n * 9 + f];
        const floatx4* p = (const floatx4*)(atom_emb + (size_t)(f * 128 + v) * 64);
        acc += p[q];
    }
    ((floatx4*)h)[(size_t)n * 16 + q] = acc;
}

// ---- CSR build (per call; ws re-poisoned) ----
__global__ void deg_count(const int* __restrict__ ei, int* __restrict__ csr) {
    int e = blockIdx.x * 256 + threadIdx.x;
    if (e < NE) atomicAdd(&csr[ei[NE + e]], 1);
}

// phase 1: per-block exclusive scan of 1024 degrees, emit block total
__global__ void scan_local(int* __restrict__ csr, int* __restrict__ bsum) {
    __shared__ int ls[256];
    int tid = threadIdx.x;
    int base = blockIdx.x * 1024 + tid * 4;
    int4 v = make_int4(0, 0, 0, 0);
    if (base + 3 < NN) {
        v = *(const int4*)(csr + base);
    } else {
        if (base + 0 < NN) v.x = csr[base + 0];
        if (base + 1 < NN) v.y = csr[base + 1];
        if (base + 2 < NN) v.z = csr[base + 2];
        if (base + 3 < NN) v.w = csr[base + 3];
    }
    int s = v.x + v.y + v.z + v.w;
    ls[tid] = s;
    __syncthreads();
    for (int d = 1; d < 256; d <<= 1) {
        int t = (tid >= d) ? ls[tid - d] : 0;
        __syncthreads();
        ls[tid] += t;
        __syncthreads();
    }
    if (tid == 255) bsum[blockIdx.x] = ls[255];
    int e0 = tid ? ls[tid - 1] : 0;
    int4 w;
    w.x = e0; w.y = e0 + v.x; w.z = w.y + v.y; w.w = w.z + v.z;
    if (base + 3 < NN) {
        *(int4*)(csr + base) = w;
    } else {
        if (base + 0 < NN) csr[base + 0] = w.x;
        if (base + 1 < NN) csr[base + 1] = w.y;
        if (base + 2 < NN) csr[base + 2] = w.z;
        if (base + 3 < NN) csr[base + 3] = w.w;
    }
}

// phase 2: exclusive scan of the 98 block totals (one block)
__global__ void scan_bsum(int* __restrict__ bsum) {
    __shared__ int ls[128];
    int tid = threadIdx.x;                     // 128 threads
    int v = (tid < 98) ? bsum[tid] : 0;
    ls[tid] = v;
    __syncthreads();
    for (int d = 1; d < 128; d <<= 1) {
        int t = (tid >= d) ? ls[tid - d] : 0;
        __syncthreads();
        ls[tid] += t;
        __syncthreads();
    }
    if (tid < 98) bsum[tid] = tid ? ls[tid - 1] : 0;
}

// phase 3: add block prefix
__global__ void scan_add(int* __restrict__ csr, const int* __restrict__ bsum) {
    int off = bsum[blockIdx.x];
    int base = blockIdx.x * 1024 + threadIdx.x * 4;
    if (base + 3 < NN) {
        int4 v = *(const int4*)(csr + base);
        v.x += off; v.y += off; v.z += off; v.w += off;
        *(int4*)(csr + base) = v;
    } else {
        for (int i = 0; i < 4; i++)
            if (base + i < NN) csr[base + i] += off;
    }
}

// packed record: src (17b) | a0 (3b) | a1 (3b) | a2 (3b)
__global__ void csr_fill(const int* __restrict__ ei, const int* __restrict__ ea,
                         int* __restrict__ csr, unsigned* __restrict__ epack) {
    int e = blockIdx.x * 256 + threadIdx.x;
    if (e >= NE) return;
    int dst = ei[NE + e];
    int pos = atomicAdd(&csr[dst], 1);
    unsigned at = (unsigned)(ea[e * 3] | (ea[e * 3 + 1] << 3) | (ea[e * 3 + 2] << 6));
    epack[pos] = (unsigned)ei[e] | (at << 17);
}

// agg[n] = (1+eps)*h[n] + sum_{e: dst==n} relu(h[src_e] + bond(e))
// HASBN: x holds prev layer's pre-BN t2; h = relu(bn2(x)) applied on the fly.
template <bool HASBN>
__global__ void gather_k(const float* __restrict__ x, const float* __restrict__ bond_emb,
                         const float* __restrict__ eps, const int* __restrict__ csr,
                         const unsigned* __restrict__ epack, int l,
                         const double* __restrict__ stats, const float* __restrict__ bn_g,
                         const float* __restrict__ bn_b, float* __restrict__ agg) {
    __shared__ float be[24 * 64];              // 6 KB: this layer's bond embeddings
    __shared__ float ca[64], cb[64];
    int tid = threadIdx.x;
    const float* bsrc = bond_emb + (size_t)l * 1536;
    for (int i = tid; i < 1536; i += 256) be[i] = bsrc[i];
    if (tid < 64) {
        if (HASBN) {
            float mean = (float)(stats[tid] / NN);
            float var  = (float)(stats[64 + tid] / NN) - mean * mean;
            float a = bn_g[(l - 1) * 64 + tid] * rsqrtf(var + 1e-5f);
            ca[tid] = a;
            cb[tid] = bn_b[(l - 1) * 64 + tid] - mean * a;
        } else {
            ca[tid] = 1.f; cb[tid] = 0.f;
        }
    }
    __syncthreads();
    int id = blockIdx.x * 256 + tid;           // NN*16 exact
    int n = id >> 4, q = id & 15;
    float s = 1.0f + eps[l];
    floatx4 cav = *(const floatx4*)&ca[q * 4];
    floatx4 cbv = *(const floatx4*)&cb[q * 4];
    floatx4 xv = ((const floatx4*)x)[(size_t)n * 16 + q];
    if (HASBN) {
        xv[0] = fmaxf(cav[0] * xv[0] + cbv[0], 0.f);
        xv[1] = fmaxf(cav[1] * xv[1] + cbv[1], 0.f);
        xv[2] = fmaxf(cav[2] * xv[2] + cbv[2], 0.f);
        xv[3] = fmaxf(cav[3] * xv[3] + cbv[3], 0.f);
    }
    floatx4 acc = xv * s;
    int k0 = n ? csr[n - 1] : 0;
    int k1 = csr[n];
    const floatx4* beq = (const floatx4*)be;
    unsigned rec = (k0 < k1) ? epack[k0] : 0u;
    for (int k = k0; k < k1; k++) {
        unsigned cur = rec;
        if (k + 1 < k1) rec = epack[k + 1];    // prefetch next record
        int src = (int)(cur & 0x1FFFFu);
        floatx4 m = ((const floatx4*)x)[(size_t)src * 16 + q];
        if (HASBN) {
            m[0] = fmaxf(cav[0] * m[0] + cbv[0], 0.f);
            m[1] = fmaxf(cav[1] * m[1] + cbv[1], 0.f);
            m[2] = fmaxf(cav[2] * m[2] + cbv[2], 0.f);
            m[3] = fmaxf(cav[3] * m[3] + cbv[3], 0.f);
        }
        m += beq[((cur >> 17) & 7u) * 16 + q];
        m += beq[(8 + ((cur >> 20) & 7u)) * 16 + q];
        m += beq[(16 + ((cur >> 23) & 7u)) * 16 + q];
        acc[0] += fmaxf(m[0], 0.f);
        acc[1] += fmaxf(m[1], 0.f);
        acc[2] += fmaxf(m[2], 0.f);
        acc[3] += fmaxf(m[3], 0.f);
    }
    ((floatx4*)agg)[(size_t)n * 16 + q] = acc;
}

// weights -> split bf16 (hi + lo), transposed: W1T [l][c(128)][k(64)], W2T [l][c(64)][k(128)]
__global__ void wcvt(const float* __restrict__ W1, const float* __restrict__ W2,
                     unsigned short* __restrict__ w1h, unsigned short* __restrict__ w1l,
                     unsigned short* __restrict__ w2h, unsigned short* __restrict__ w2l) {
    int id = blockIdx.x * 256 + threadIdx.x;   // 65536
    if (id < 32768) {
        int l = id >> 13, rem = id & 8191, c = rem >> 6, k = rem & 63;
        float w = W1[l * 8192 + k * 128 + c];
        unsigned short hh = f2bf(w);
        w1h[id] = hh; w1l[id] = f2bf(w - bf2f(hh));
    } else {
        int id2 = id - 32768;
        int l = id2 >> 13, rem = id2 & 8191, c = rem >> 7, k = rem & 127;
        float w = W2[l * 8192 + k * 64 + c];
        unsigned short hh = f2bf(w);
        w2h[id2] = hh; w2l[id2] = f2bf(w - bf2f(hh));
    }
}

#define MFMA __builtin_amdgcn_mfma_f32_16x16x32_bf16

// t1[N][128] = z[N][64] @ W1 + b1  (split-bf16 ~ fp32 accurate) + fused colstats
__launch_bounds__(256)
__global__ void mlp1(const float* __restrict__ z, const unsigned short* __restrict__ w1h,
                     const unsigned short* __restrict__ w1l, const float* __restrict__ b1,
                     int l, float* __restrict__ t1, double* __restrict__ stats) {
    __shared__ char smem[55296];
    unsigned short* zbh = (unsigned short*)smem;      // 64*72
    unsigned short* zbl = zbh + 64 * 72;
    unsigned short* wth = zbl + 64 * 72;              // 128*72
    unsigned short* wtl = wth + 128 * 72;
    int tid = threadIdx.x;
    int base = blockIdx.x * 64;
    const unsigned short* wsh = w1h + l * 8192;
    const unsigned short* wsl = w1l + l * 8192;
    for (int it = 0; it < 4; it++) {
        int chunk = it * 256 + tid;
        int c = chunk >> 3, k0 = (chunk & 7) * 8;
        *(uint4*)&wth[c * 72 + k0] = *(const uint4*)(wsh + chunk * 8);
        *(uint4*)&wtl[c * 72 + k0] = *(const uint4*)(wsl + chunk * 8);
    }
    for (int it = 0; it < 8; it++) {
        int idx2 = (it * 256 + tid) * 2;
        int n = idx2 >> 6, col = idx2 & 63;
        int node = base + n;
        float2 v = make_float2(0.f, 0.f);
        if (node < NN) v = ((const float2*)z)[(size_t)node * 32 + (col >> 1)];
        unsigned short hx = f2bf(v.x), hy = f2bf(v.y);
        zbh[n * 72 + col] = hx;     zbh[n * 72 + col + 1] = hy;
        zbl[n * 72 + col] = f2bf(v.x - bf2f(hx));
        zbl[n * 72 + col + 1] = f2bf(v.y - bf2f(hy));
    }
    __syncthreads();
    int wv = tid >> 6, lane = tid & 63, m = lane & 15, qd = lane >> 4;
    short8 ah0 = *(const short8*)&zbh[(wv * 16 + m) * 72 + qd * 8];
    short8 ah1 = *(const short8*)&zbh[(wv * 16 + m) * 72 + 32 + qd * 8];
    short8 al0 = *(const short8*)&zbl[(wv * 16 + m) * 72 + qd * 8];
    short8 al1 = *(const short8*)&zbl[(wv * 16 + m) * 72 + 32 + qd * 8];
    floatx4 acc[8];
    for (int t = 0; t < 8; t++) {
        short8 bh0 = *(const short8*)&wth[(t * 16 + m) * 72 + qd * 8];
        short8 bh1 = *(const short8*)&wth[(t * 16 + m) * 72 + 32 + qd * 8];
        short8 bl0 = *(const short8*)&wtl[(t * 16 + m) * 72 + qd * 8];
        short8 bl1 = *(const short8*)&wtl[(t * 16 + m) * 72 + 32 + qd * 8];
        floatx4 c0 = {0.f, 0.f, 0.f, 0.f};
        c0 = MFMA(ah0, bh0, c0, 0, 0, 0);
        c0 = MFMA(ah0, bl0, c0, 0, 0, 0);
        c0 = MFMA(al0, bh0, c0, 0, 0, 0);
        c0 = MFMA(ah1, bh1, c0, 0, 0, 0);
        c0 = MFMA(ah1, bl1, c0, 0, 0, 0);
        c0 = MFMA(al1, bh1, c0, 0, 0, 0);
        acc[t] = c0;
    }
    __syncthreads();                                   // reuse zb region for reduction
    float* redS = (float*)smem;                        // [128][16]
    float* redQ = redS + 2048;
    const float* bias = b1 + l * 128;
    int g = wv * 4 + qd;
    for (int t = 0; t < 8; t++) {
        int col = t * 16 + m;
        float bv = bias[col];
        float s = 0.f, ss = 0.f;
        for (int r = 0; r < 4; r++) {
            int node = base + wv * 16 + qd * 4 + r;
            if (node < NN) {
                float v = acc[t][r] + bv;
                t1[(size_t)node * 128 + col] = v;
                s += v; ss += v * v;
            }
        }
        redS[col * 16 + g] = s;
        redQ[col * 16 + g] = ss;
    }
    __syncthreads();
    if (tid < 128) {
        float s = 0.f, ss = 0.f;
        for (int gg = 0; gg < 16; gg++) { s += redS[tid * 16 + gg]; ss += redQ[tid * 16 + gg]; }
        atomicAdd(&stats[tid], (double)s);
        atomicAdd(&stats[128 + tid], (double)ss);
    }
}

// t2[N][64] = relu(bn1(t1)) @ W2 + b2 (split-bf16) + fused colstats
__launch_bounds__(256)
__global__ void mlp2(const float* __restrict__ t1, const unsigned short* __restrict__ w2h,
                     const unsigned short* __restrict__ w2l, const float* __restrict__ b2,
                     const float* __restrict__ bn_g, const float* __restrict__ bn_b,
                     const double* __restrict__ stats1, int l, float* __restrict__ t2,
                     double* __restrict__ stats2) {
    __shared__ char smem[70656];
    unsigned short* rbh = (unsigned short*)smem;       // 64*136
    unsigned short* rbl = rbh + 64 * 136;
    unsigned short* wth = rbl + 64 * 136;
    unsigned short* wtl = wth + 64 * 136;
    float* ca = (float*)(smem + 69632);                // 128 + 128
    float* cb = ca + 128;
    int tid = threadIdx.x;
    if (tid < 128) {
        float mean = (float)(stats1[tid] / NN);
        float var  = (float)(stats1[128 + tid] / NN) - mean * mean;
        float a = bn_g[l * 128 + tid] * rsqrtf(var + 1e-5f);
        ca[tid] = a;
        cb[tid] = bn_b[l * 128 + tid] - mean * a;
    }
    const unsigned short* wsh = w2h + l * 8192;
    const unsigned short* wsl = w2l + l * 8192;
    for (int it = 0; it < 4; it++) {
        int chunk = it * 256 + tid;
        int c = chunk >> 4, k0 = (chunk & 15) * 8;
        *(uint4*)&wth[c * 136 + k0] = *(const uint4*)(wsh + chunk * 8);
        *(uint4*)&wtl[c * 136 + k0] = *(const uint4*)(wsl + chunk * 8);
    }
    __syncthreads();                                   // ca/cb visible
    int base = blockIdx.x * 64;
    for (int it = 0; it < 16; it++) {
        int idx2 = (it * 256 + tid) * 2;
        int n = idx2 >> 7, c = idx2 & 127;
        int node = base + n;
        float2 v = make_float2(0.f, 0.f);
        if (node < NN) v = ((const float2*)t1)[(size_t)node * 64 + (c >> 1)];
        float rx = fmaxf(ca[c] * v.x + cb[c], 0.f);
        float ry = fmaxf(ca[c + 1] * v.y + cb[c + 1], 0.f);
        unsigned short hx = f2bf(rx), hy = f2bf(ry);
        rbh[n * 136 + c] = hx;     rbh[n * 136 + c + 1] = hy;
        rbl[n * 136 + c] = f2bf(rx - bf2f(hx));
        rbl[n * 136 + c + 1] = f2bf(ry - bf2f(hy));
    }
    __syncthreads();
    int wv = tid >> 6, lane = tid & 63, m = lane & 15, qd = lane >> 4;
    short8 ah[4], al[4];
    for (int kh = 0; kh < 4; kh++) {
        ah[kh] = *(const short8*)&rbh[(wv * 16 + m) * 136 + kh * 32 + qd * 8];
        al[kh] = *(const short8*)&rbl[(wv * 16 + m) * 136 + kh * 32 + qd * 8];
    }
    floatx4 acc[4];
    for (int t = 0; t < 4; t++) {
        floatx4 c0 = {0.f, 0.f, 0.f, 0.f};
        for (int kh = 0; kh < 4; kh++) {
            short8 bh = *(const short8*)&wth[(t * 16 + m) * 136 + kh * 32 + qd * 8];
            short8 bl = *(const short8*)&wtl[(t * 16 + m) * 136 + kh * 32 + qd * 8];
            c0 = MFMA(ah[kh], bh, c0, 0, 0, 0);
            c0 = MFMA(ah[kh], bl, c0, 0, 0, 0);
            c0 = MFMA(al[kh], bh, c0, 0, 0, 0);
        }
        acc[t] = c0;
    }
    __syncthreads();                                   // reuse rb region
    float* redS = (float*)smem;                        // [64][16]
    float* redQ = redS + 1024;
    const float* bias = b2 + l * 64;
    int g = wv * 4 + qd;
    for (int t = 0; t < 4; t++) {
        int col = t * 16 + m;
        float bv = bias[col];
        float s = 0.f, ss = 0.f;
        for (int r = 0; r < 4; r++) {
            int node = base + wv * 16 + qd * 4 + r;
            if (node < NN) {
                float v = acc[t][r] + bv;
                t2[(size_t)node * 64 + col] = v;
                s += v; ss += v * v;
            }
        }
        redS[col * 16 + g] = s;
        redQ[col * 16 + g] = ss;
    }
    __syncthreads();
    if (tid < 64) {
        float s = 0.f, ss = 0.f;
        for (int gg = 0; gg < 16; gg++) { s += redS[tid * 16 + gg]; ss += redQ[tid * 16 + gg]; }
        atomicAdd(&stats2[tid], (double)s);
        atomicAdd(&stats2[64 + tid], (double)ss);
    }
}

// final layer: out = bn2(t2), plus mean-pool atomics
__global__ void bnapply_last(const float* __restrict__ t2, const float* __restrict__ bn_g,
                             const float* __restrict__ bn_b, const double* __restrict__ stats,
                             float* __restrict__ out, float* __restrict__ gsum,
                             float* __restrict__ gcnt, const int* __restrict__ batch) {
    __shared__ float ca[64], cb[64];
    int tid = threadIdx.x;
    if (tid < 64) {
        float mean = (float)(stats[tid] / NN);
        float var  = (float)(stats[64 + tid] / NN) - mean * mean;
        float a = bn_g[3 * 64 + tid] * rsqrtf(var + 1e-5f);
        ca[tid] = a;
        cb[tid] = bn_b[3 * 64 + tid] - mean * a;
    }
    __syncthreads();
    size_t base = (size_t)blockIdx.x * 4096;
    for (int it = 0; it < 16; it++) {
        size_t idx = base + it * 256 + tid;
        if (idx >= (size_t)NN * 64) return;
        int c = (int)(idx & 63);
        float v = ca[c] * t2[idx] + cb[c];
        out[idx] = v;
        int g = batch[idx >> 6];
        atomicAdd(&gsum[(size_t)g * 64 + c], v);
        if (c == 0) atomicAdd(&gcnt[g], 1.0f);
    }
}

__global__ void pool_div(const float* __restrict__ gsum, const float* __restrict__ gcnt,
                         float* __restrict__ out) {
    int id = blockIdx.x * 256 + threadIdx.x;   // NB*64
    int g = id >> 6;
    out[(size_t)NN * 64 + id] = gsum[id] / (gcnt[g] + 1e-9f);
}

extern "C" void kernel_launch(void* const* d_in, const int* in_sizes, int n_in,
                              void* d_out, int out_size, void* d_ws, size_t ws_size,
                              hipStream_t stream) {
    const float* atom_emb = (const float*)d_in[0];
    const float* bond_emb = (const float*)d_in[1];
    const float* eps      = (const float*)d_in[2];
    const float* W1       = (const float*)d_in[3];
    const float* b1       = (const float*)d_in[4];
    const float* bn1_g    = (const float*)d_in[5];
    const float* bn1_b    = (const float*)d_in[6];
    const float* W2       = (const float*)d_in[7];
    const float* b2       = (const float*)d_in[8];
    const float* bn2_g    = (const float*)d_in[9];
    const float* bn2_b    = (const float*)d_in[10];
    const int* x_feat     = (const int*)d_in[11];
    const int* edge_index = (const int*)d_in[12];
    const int* edge_attr  = (const int*)d_in[13];
    const int* batch      = (const int*)d_in[14];
    float* out = (float*)d_out;

    char* ws = (char*)d_ws;
    // ---- zero region (one memset) ----
    double* stats = (double*)ws;  ws += 2048 * 8;            // 8 slots x 256 doubles
    float* gsum   = (float*)ws;   ws += (size_t)NB * 64 * 4;
    float* gcnt   = (float*)ws;   ws += NB * 4;
    int* csr      = (int*)ws;     ws += (size_t)NN * 4;
    size_t zbytes = (size_t)(ws - (char*)d_ws);
    // ---- rest ----
    int* bsum       = (int*)ws;       ws += 128 * 4;
    unsigned* epack = (unsigned*)ws;  ws += (size_t)NE * 4;
    float* xbuf = (float*)ws;     ws += (size_t)NN * 64 * 4;   // h (layer 0) / t2 (layers>=1)
    float* agg  = (float*)ws;     ws += (size_t)NN * 64 * 4;
    float* t1   = (float*)ws;     ws += (size_t)NN * 128 * 4;
    unsigned short* w1h = (unsigned short*)ws; ws += 32768 * 2;
    unsigned short* w1l = (unsigned short*)ws; ws += 32768 * 2;
    unsigned short* w2h = (unsigned short*)ws; ws += 32768 * 2;
    unsigned short* w2l = (unsigned short*)ws; ws += 32768 * 2;

    hipMemsetAsync((void*)stats, 0, zbytes, stream);

    wcvt<<<256, 256, 0, stream>>>(W1, W2, w1h, w1l, w2h, w2l);
    deg_count<<<4883, 256, 0, stream>>>(edge_index, csr);
    scan_local<<<98, 256, 0, stream>>>(csr, bsum);
    scan_bsum<<<1, 128, 0, stream>>>(bsum);
    scan_add<<<98, 256, 0, stream>>>(csr, bsum);
    csr_fill<<<4883, 256, 0, stream>>>(edge_index, edge_attr, csr, epack);
    atom_encode<<<6250, 256, 0, stream>>>(atom_emb, x_feat, xbuf);

    for (int l = 0; l < 4; l++) {
        double* s1 = stats + (size_t)(l * 2) * 256;
        double* s2 = stats + (size_t)(l * 2 + 1) * 256;
        if (l == 0) {
            gather_k<false><<<6250, 256, 0, stream>>>(xbuf, bond_emb, eps, csr, epack, l,
                                                      nullptr, nullptr, nullptr, agg);
        } else {
            double* sp = stats + (size_t)((l - 1) * 2 + 1) * 256;
            gather_k<true><<<6250, 256, 0, stream>>>(xbuf, bond_emb, eps, csr, epack, l,
                                                     sp, bn2_g, bn2_b, agg);
        }
        mlp1<<<1563, 256, 0, stream>>>(agg, w1h, w1l, b1, l, t1, s1);
        mlp2<<<1563, 256, 0, stream>>>(t1, w2h, w2l, b2, bn1_g, bn1_b, s1, l, xbuf, s2);
    }
    bnapply_last<<<1563, 256, 0, stream>>>(xbuf, bn2_g, bn2_b,
                                           stats + (size_t)(3 * 2 + 1) * 256,
                                           out, gsum, gcnt, batch);
    pool_div<<<512, 256, 0, stream>>>(gsum, gcnt, out);
}

// Round 5
// 993.597 us; speedup vs baseline: 1.0092x; 1.0092x over previous
//
#include <hip/hip_runtime.h>

#define NN 100000
#define NE 1250000
#define NB 2048

typedef __attribute__((ext_vector_type(8))) short short8;
typedef __attribute__((ext_vector_type(4))) float floatx4;

__device__ inline unsigned short f2bf(float f) {
    unsigned u = __float_as_uint(f);
    u = u + 0x7fffu + ((u >> 16) & 1u);   // RNE
    return (unsigned short)(u >> 16);
}
__device__ inline float bf2f(unsigned short h) {
    return __uint_as_float(((unsigned)h) << 16);
}

// h[n][d] = sum_f atom_emb[f][x_feat[n][f]][d]
__global__ void atom_encode(const float* __restrict__ atom_emb,
                            const int* __restrict__ x_feat,
                            float* __restrict__ h) {
    int id = blockIdx.x * 256 + threadIdx.x;   // N*16 exact
    int n = id >> 4, q = id & 15;
    floatx4 acc = {0.f, 0.f, 0.f, 0.f};
    for (int f = 0; f < 9; f++) {
        int v = x_feat[n * 9 + f];
        const floatx4* p = (const floatx4*)(atom_emb + (size_t)(f * 128 + v) * 64);
        acc += p[q];
    }
    ((floatx4*)h)[(size_t)n * 16 + q] = acc;
}

// ---- CSR build (per call; ws re-poisoned) ----
__global__ void deg_count(const int* __restrict__ ei, int* __restrict__ csr) {
    int e = blockIdx.x * 256 + threadIdx.x;
    if (e < NE) atomicAdd(&csr[ei[NE + e]], 1);
}

// phase 1: per-block exclusive scan of 1024 degrees, emit block total
__global__ void scan_local(int* __restrict__ csr, int* __restrict__ bsum) {
    __shared__ int ls[256];
    int tid = threadIdx.x;
    int base = blockIdx.x * 1024 + tid * 4;
    int4 v = make_int4(0, 0, 0, 0);
    if (base + 3 < NN) {
        v = *(const int4*)(csr + base);
    } else {
        if (base + 0 < NN) v.x = csr[base + 0];
        if (base + 1 < NN) v.y = csr[base + 1];
        if (base + 2 < NN) v.z = csr[base + 2];
        if (base + 3 < NN) v.w = csr[base + 3];
    }
    int s = v.x + v.y + v.z + v.w;
    ls[tid] = s;
    __syncthreads();
    for (int d = 1; d < 256; d <<= 1) {
        int t = (tid >= d) ? ls[tid - d] : 0;
        __syncthreads();
        ls[tid] += t;
        __syncthreads();
    }
    if (tid == 255) bsum[blockIdx.x] = ls[255];
    int e0 = tid ? ls[tid - 1] : 0;
    int4 w;
    w.x = e0; w.y = e0 + v.x; w.z = w.y + v.y; w.w = w.z + v.z;
    if (base + 3 < NN) {
        *(int4*)(csr + base) = w;
    } else {
        if (base + 0 < NN) csr[base + 0] = w.x;
        if (base + 1 < NN) csr[base + 1] = w.y;
        if (base + 2 < NN) csr[base + 2] = w.z;
        if (base + 3 < NN) csr[base + 3] = w.w;
    }
}

// phase 2: exclusive scan of the 98 block totals (one block)
__global__ void scan_bsum(int* __restrict__ bsum) {
    __shared__ int ls[128];
    int tid = threadIdx.x;                     // 128 threads
    int v = (tid < 98) ? bsum[tid] : 0;
    ls[tid] = v;
    __syncthreads();
    for (int d = 1; d < 128; d <<= 1) {
        int t = (tid >= d) ? ls[tid - d] : 0;
        __syncthreads();
        ls[tid] += t;
        __syncthreads();
    }
    if (tid < 98) bsum[tid] = tid ? ls[tid - 1] : 0;
}

// phase 3: add block prefix
__global__ void scan_add(int* __restrict__ csr, const int* __restrict__ bsum) {
    int off = bsum[blockIdx.x];
    int base = blockIdx.x * 1024 + threadIdx.x * 4;
    if (base + 3 < NN) {
        int4 v = *(const int4*)(csr + base);
        v.x += off; v.y += off; v.z += off; v.w += off;
        *(int4*)(csr + base) = v;
    } else {
        for (int i = 0; i < 4; i++)
            if (base + i < NN) csr[base + i] += off;
    }
}

// packed record: src (17b) | a0 (3b) | a1 (3b) | a2 (3b)
__global__ void csr_fill(const int* __restrict__ ei, const int* __restrict__ ea,
                         int* __restrict__ csr, unsigned* __restrict__ epack) {
    int e = blockIdx.x * 256 + threadIdx.x;
    if (e >= NE) return;
    int dst = ei[NE + e];
    int pos = atomicAdd(&csr[dst], 1);
    unsigned at = (unsigned)(ea[e * 3] | (ea[e * 3 + 1] << 3) | (ea[e * 3 + 2] << 6));
    epack[pos] = (unsigned)ei[e] | (at << 17);
}

// agg[n] = (1+eps)*h[n] + sum_{e: dst==n} relu(h[src_e] + bond(e))
// HASBN: x holds prev layer's pre-BN t2; h = relu(bn2(x)) applied on the fly.
template <bool HASBN>
__global__ void gather_k(const float* __restrict__ x, const float* __restrict__ bond_emb,
                         const float* __restrict__ eps, const int* __restrict__ csr,
                         const unsigned* __restrict__ epack, int l,
                         const double* __restrict__ stats, const float* __restrict__ bn_g,
                         const float* __restrict__ bn_b, float* __restrict__ agg) {
    __shared__ float be[24 * 64];              // 6 KB: this layer's bond embeddings
    __shared__ float ca[64], cb[64];
    int tid = threadIdx.x;
    const float* bsrc = bond_emb + (size_t)l * 1536;
    for (int i = tid; i < 1536; i += 256) be[i] = bsrc[i];
    if (tid < 64) {
        if (HASBN) {
            float mean = (float)(stats[tid] / NN);
            float var  = (float)(stats[64 + tid] / NN) - mean * mean;
            float a = bn_g[(l - 1) * 64 + tid] * rsqrtf(var + 1e-5f);
            ca[tid] = a;
            cb[tid] = bn_b[(l - 1) * 64 + tid] - mean * a;
        } else {
            ca[tid] = 1.f; cb[tid] = 0.f;
        }
    }
    __syncthreads();
    int id = blockIdx.x * 256 + tid;           // NN*16 exact
    int n = id >> 4, q = id & 15;
    float s = 1.0f + eps[l];
    floatx4 cav = *(const floatx4*)&ca[q * 4];
    floatx4 cbv = *(const floatx4*)&cb[q * 4];
    floatx4 xv = ((const floatx4*)x)[(size_t)n * 16 + q];
    if (HASBN) {
        xv[0] = fmaxf(cav[0] * xv[0] + cbv[0], 0.f);
        xv[1] = fmaxf(cav[1] * xv[1] + cbv[1], 0.f);
        xv[2] = fmaxf(cav[2] * xv[2] + cbv[2], 0.f);
        xv[3] = fmaxf(cav[3] * xv[3] + cbv[3], 0.f);
    }
    floatx4 acc = xv * s;
    int k0 = n ? csr[n - 1] : 0;
    int k1 = csr[n];
    const floatx4* beq = (const floatx4*)be;
    unsigned rec = (k0 < k1) ? epack[k0] : 0u;
    for (int k = k0; k < k1; k++) {
        unsigned cur = rec;
        if (k + 1 < k1) rec = epack[k + 1];    // prefetch next record
        int src = (int)(cur & 0x1FFFFu);
        floatx4 m = ((const floatx4*)x)[(size_t)src * 16 + q];
        if (HASBN) {
            m[0] = fmaxf(cav[0] * m[0] + cbv[0], 0.f);
            m[1] = fmaxf(cav[1] * m[1] + cbv[1], 0.f);
            m[2] = fmaxf(cav[2] * m[2] + cbv[2], 0.f);
            m[3] = fmaxf(cav[3] * m[3] + cbv[3], 0.f);
        }
        m += beq[((cur >> 17) & 7u) * 16 + q];
        m += beq[(8 + ((cur >> 20) & 7u)) * 16 + q];
        m += beq[(16 + ((cur >> 23) & 7u)) * 16 + q];
        acc[0] += fmaxf(m[0], 0.f);
        acc[1] += fmaxf(m[1], 0.f);
        acc[2] += fmaxf(m[2], 0.f);
        acc[3] += fmaxf(m[3], 0.f);
    }
    ((floatx4*)agg)[(size_t)n * 16 + q] = acc;
}

// weights -> split bf16 (hi + lo), transposed: W1T [l][c(128)][k(64)], W2T [l][c(64)][k(128)]
__global__ void wcvt(const float* __restrict__ W1, const float* __restrict__ W2,
                     unsigned short* __restrict__ w1h, unsigned short* __restrict__ w1l,
                     unsigned short* __restrict__ w2h, unsigned short* __restrict__ w2l) {
    int id = blockIdx.x * 256 + threadIdx.x;   // 65536
    if (id < 32768) {
        int l = id >> 13, rem = id & 8191, c = rem >> 6, k = rem & 63;
        float w = W1[l * 8192 + k * 128 + c];
        unsigned short hh = f2bf(w);
        w1h[id] = hh; w1l[id] = f2bf(w - bf2f(hh));
    } else {
        int id2 = id - 32768;
        int l = id2 >> 13, rem = id2 & 8191, c = rem >> 7, k = rem & 127;
        float w = W2[l * 8192 + k * 64 + c];
        unsigned short hh = f2bf(w);
        w2h[id2] = hh; w2l[id2] = f2bf(w - bf2f(hh));
    }
}

#define MFMA __builtin_amdgcn_mfma_f32_16x16x32_bf16

// BN1 stats pass: t1 = z@W1+b1 computed, column sums/sumsq -> stats1. t1 NOT stored.
__launch_bounds__(256)
__global__ void mlp1stat(const float* __restrict__ z, const unsigned short* __restrict__ w1h,
                         const unsigned short* __restrict__ w1l, const float* __restrict__ b1,
                         int l, double* __restrict__ stats) {
    __shared__ char smem[55296];
    unsigned short* zbh = (unsigned short*)smem;      // 64*72
    unsigned short* zbl = zbh + 64 * 72;
    unsigned short* wth = zbl + 64 * 72;              // 128*72
    unsigned short* wtl = wth + 128 * 72;
    int tid = threadIdx.x;
    int base = blockIdx.x * 64;
    const unsigned short* wsh = w1h + l * 8192;
    const unsigned short* wsl = w1l + l * 8192;
    for (int it = 0; it < 4; it++) {
        int chunk = it * 256 + tid;
        int c = chunk >> 3, k0 = (chunk & 7) * 8;
        *(uint4*)&wth[c * 72 + k0] = *(const uint4*)(wsh + chunk * 8);
        *(uint4*)&wtl[c * 72 + k0] = *(const uint4*)(wsl + chunk * 8);
    }
    for (int it = 0; it < 8; it++) {
        int idx2 = (it * 256 + tid) * 2;
        int n = idx2 >> 6, col = idx2 & 63;
        int node = base + n;
        float2 v = make_float2(0.f, 0.f);
        if (node < NN) v = ((const float2*)z)[(size_t)node * 32 + (col >> 1)];
        unsigned short hx = f2bf(v.x), hy = f2bf(v.y);
        zbh[n * 72 + col] = hx;     zbh[n * 72 + col + 1] = hy;
        zbl[n * 72 + col] = f2bf(v.x - bf2f(hx));
        zbl[n * 72 + col + 1] = f2bf(v.y - bf2f(hy));
    }
    __syncthreads();
    int wv = tid >> 6, lane = tid & 63, m = lane & 15, qd = lane >> 4;
    short8 ah0 = *(const short8*)&zbh[(wv * 16 + m) * 72 + qd * 8];
    short8 ah1 = *(const short8*)&zbh[(wv * 16 + m) * 72 + 32 + qd * 8];
    short8 al0 = *(const short8*)&zbl[(wv * 16 + m) * 72 + qd * 8];
    short8 al1 = *(const short8*)&zbl[(wv * 16 + m) * 72 + 32 + qd * 8];
    floatx4 acc[8];
    for (int t = 0; t < 8; t++) {
        short8 bh0 = *(const short8*)&wth[(t * 16 + m) * 72 + qd * 8];
        short8 bh1 = *(const short8*)&wth[(t * 16 + m) * 72 + 32 + qd * 8];
        short8 bl0 = *(const short8*)&wtl[(t * 16 + m) * 72 + qd * 8];
        short8 bl1 = *(const short8*)&wtl[(t * 16 + m) * 72 + 32 + qd * 8];
        floatx4 c0 = {0.f, 0.f, 0.f, 0.f};
        c0 = MFMA(ah0, bh0, c0, 0, 0, 0);
        c0 = MFMA(ah0, bl0, c0, 0, 0, 0);
        c0 = MFMA(al0, bh0, c0, 0, 0, 0);
        c0 = MFMA(ah1, bh1, c0, 0, 0, 0);
        c0 = MFMA(ah1, bl1, c0, 0, 0, 0);
        c0 = MFMA(al1, bh1, c0, 0, 0, 0);
        acc[t] = c0;
    }
    __syncthreads();                                   // reuse zb region for reduction
    float* redS = (float*)smem;                        // [128][16]
    float* redQ = redS + 2048;
    const float* bias = b1 + l * 128;
    int g = wv * 4 + qd;
    for (int t = 0; t < 8; t++) {
        int col = t * 16 + m;
        float bv = bias[col];
        float s = 0.f, ss = 0.f;
        for (int r = 0; r < 4; r++) {
            int node = base + wv * 16 + qd * 4 + r;
            if (node < NN) {
                float v = acc[t][r] + bv;
                s += v; ss += v * v;
            }
        }
        redS[col * 16 + g] = s;
        redQ[col * 16 + g] = ss;
    }
    __syncthreads();
    if (tid < 128) {
        float s = 0.f, ss = 0.f;
        for (int gg = 0; gg < 16; gg++) { s += redS[tid * 16 + gg]; ss += redQ[tid * 16 + gg]; }
        atomicAdd(&stats[tid], (double)s);
        atomicAdd(&stats[128 + tid], (double)ss);
    }
}

// Fused MLP: z -> GEMM1 (recomputed, identical to mlp1stat) -> bn1+relu -> GEMM2 -> t2
// t1 never leaves registers/LDS. Fused t2 colstats -> stats2.
__launch_bounds__(256)
__global__ void mlp_fused(const float* __restrict__ z,
                          const unsigned short* __restrict__ w1h, const unsigned short* __restrict__ w1l,
                          const float* __restrict__ b1,
                          const unsigned short* __restrict__ w2h, const unsigned short* __restrict__ w2l,
                          const float* __restrict__ b2,
                          const float* __restrict__ bn_g, const float* __restrict__ bn_b,
                          const double* __restrict__ stats1, int l,
                          float* __restrict__ t2, double* __restrict__ stats2) {
    __shared__ char smem[70656];
    // phase A layout (shorts): zbh[0..4608) zbl[4608..9216) wth[9216..18432) wtl[18432..27648)
    unsigned short* zbh = (unsigned short*)smem;
    unsigned short* zbl = zbh + 64 * 72;
    unsigned short* wth = zbl + 64 * 72;
    unsigned short* wtl = wth + 128 * 72;
    // phase B layout (shorts): rbh[0..8704) rbl[8704..17408) w2th[17408..26112) w2tl[26112..34816)
    unsigned short* rbh  = (unsigned short*)smem;
    unsigned short* rbl  = rbh + 64 * 136;
    unsigned short* w2th = rbl + 64 * 136;
    unsigned short* w2tl = w2th + 64 * 136;
    float* ca = (float*)(smem + 69632);                // [128] + [128]
    float* cb = ca + 128;
    int tid = threadIdx.x;
    int base = blockIdx.x * 64;

    // bn1 coefficients (b1 folded in: rv = ca*acc + cb)
    if (tid < 128) {
        float mean = (float)(stats1[tid] / NN);
        float var  = (float)(stats1[128 + tid] / NN) - mean * mean;
        float a = bn_g[l * 128 + tid] * rsqrtf(var + 1e-5f);
        ca[tid] = a;
        cb[tid] = bn_b[l * 128 + tid] - mean * a + a * b1[l * 128 + tid];
    }
    // phase A staging: W1 + z (identical to mlp1stat -> bitwise-same t1)
    const unsigned short* wsh = w1h + l * 8192;
    const unsigned short* wsl = w1l + l * 8192;
    for (int it = 0; it < 4; it++) {
        int chunk = it * 256 + tid;
        int c = chunk >> 3, k0 = (chunk & 7) * 8;
        *(uint4*)&wth[c * 72 + k0] = *(const uint4*)(wsh + chunk * 8);
        *(uint4*)&wtl[c * 72 + k0] = *(const uint4*)(wsl + chunk * 8);
    }
    for (int it = 0; it < 8; it++) {
        int idx2 = (it * 256 + tid) * 2;
        int n = idx2 >> 6, col = idx2 & 63;
        int node = base + n;
        float2 v = make_float2(0.f, 0.f);
        if (node < NN) v = ((const float2*)z)[(size_t)node * 32 + (col >> 1)];
        unsigned short hx = f2bf(v.x), hy = f2bf(v.y);
        zbh[n * 72 + col] = hx;     zbh[n * 72 + col + 1] = hy;
        zbl[n * 72 + col] = f2bf(v.x - bf2f(hx));
        zbl[n * 72 + col + 1] = f2bf(v.y - bf2f(hy));
    }
    // prefetch W2 into registers (lands in LDS after the post-GEMM1 barrier)
    const unsigned short* w2sh = w2h + l * 8192;
    const unsigned short* w2sl = w2l + l * 8192;
    uint4 preH[4], preL[4];
    for (int it = 0; it < 4; it++) {
        preH[it] = *(const uint4*)(w2sh + (it * 256 + tid) * 8);
        preL[it] = *(const uint4*)(w2sl + (it * 256 + tid) * 8);
    }
    __syncthreads();
    int wv = tid >> 6, lane = tid & 63, m = lane & 15, qd = lane >> 4;
    short8 ah0 = *(const short8*)&zbh[(wv * 16 + m) * 72 + qd * 8];
    short8 ah1 = *(const short8*)&zbh[(wv * 16 + m) * 72 + 32 + qd * 8];
    short8 al0 = *(const short8*)&zbl[(wv * 16 + m) * 72 + qd * 8];
    short8 al1 = *(const short8*)&zbl[(wv * 16 + m) * 72 + 32 + qd * 8];
    floatx4 acc1[8];
    for (int t = 0; t < 8; t++) {
        short8 bh0 = *(const short8*)&wth[(t * 16 + m) * 72 + qd * 8];
        short8 bh1 = *(const short8*)&wth[(t * 16 + m) * 72 + 32 + qd * 8];
        short8 bl0 = *(const short8*)&wtl[(t * 16 + m) * 72 + qd * 8];
        short8 bl1 = *(const short8*)&wtl[(t * 16 + m) * 72 + 32 + qd * 8];
        floatx4 c0 = {0.f, 0.f, 0.f, 0.f};
        c0 = MFMA(ah0, bh0, c0, 0, 0, 0);
        c0 = MFMA(ah0, bl0, c0, 0, 0, 0);
        c0 = MFMA(al0, bh0, c0, 0, 0, 0);
        c0 = MFMA(ah1, bh1, c0, 0, 0, 0);
        c0 = MFMA(ah1, bl1, c0, 0, 0, 0);
        c0 = MFMA(al1, bh1, c0, 0, 0, 0);
        acc1[t] = c0;
    }
    __syncthreads();                                   // z/W1 LDS dead
    // phase B staging: W2 from regs, r = relu(bn1(t1)) split-bf16
    for (int it = 0; it < 4; it++) {
        int chunk = it * 256 + tid;
        int c = chunk >> 4, k0 = (chunk & 15) * 8;
        *(uint4*)&w2th[c * 136 + k0] = preH[it];
        *(uint4*)&w2tl[c * 136 + k0] = preL[it];
    }
    for (int t = 0; t < 8; t++) {
        int col = t * 16 + m;
        float a = ca[col], b = cb[col];
        for (int r = 0; r < 4; r++) {
            int row = wv * 16 + qd * 4 + r;
            float rv = fmaxf(a * acc1[t][r] + b, 0.f);
            unsigned short hh = f2bf(rv);
            rbh[row * 136 + col] = hh;
            rbl[row * 136 + col] = f2bf(rv - bf2f(hh));
        }
    }
    __syncthreads();
    short8 ah[4], al[4];
    for (int kh = 0; kh < 4; kh++) {
        ah[kh] = *(const short8*)&rbh[(wv * 16 + m) * 136 + kh * 32 + qd * 8];
        al[kh] = *(const short8*)&rbl[(wv * 16 + m) * 136 + kh * 32 + qd * 8];
    }
    floatx4 acc2[4];
    for (int t = 0; t < 4; t++) {
        floatx4 c0 = {0.f, 0.f, 0.f, 0.f};
        for (int kh = 0; kh < 4; kh++) {
            short8 bh = *(const short8*)&w2th[(t * 16 + m) * 136 + kh * 32 + qd * 8];
            short8 bl = *(const short8*)&w2tl[(t * 16 + m) * 136 + kh * 32 + qd * 8];
            c0 = MFMA(ah[kh], bh, c0, 0, 0, 0);
            c0 = MFMA(ah[kh], bl, c0, 0, 0, 0);
            c0 = MFMA(al[kh], bh, c0, 0, 0, 0);
        }
        acc2[t] = c0;
    }
    __syncthreads();                                   // rb region dead -> reduction overlay
    float* redS = (float*)smem;                        // [64][16]
    float* redQ = redS + 1024;
    const float* bias = b2 + l * 64;
    int g = wv * 4 + qd;
    for (int t = 0; t < 4; t++) {
        int col = t * 16 + m;
        float bv = bias[col];
        float s = 0.f, ss = 0.f;
        for (int r = 0; r < 4; r++) {
            int node = base + wv * 16 + qd * 4 + r;
            if (node < NN) {
                float v = acc2[t][r] + bv;
                t2[(size_t)node * 64 + col] = v;
                s += v; ss += v * v;
            }
        }
        redS[col * 16 + g] = s;
        redQ[col * 16 + g] = ss;
    }
    __syncthreads();
    if (tid < 64) {
        float s = 0.f, ss = 0.f;
        for (int gg = 0; gg < 16; gg++) { s += redS[tid * 16 + gg]; ss += redQ[tid * 16 + gg]; }
        atomicAdd(&stats2[tid], (double)s);
        atomicAdd(&stats2[64 + tid], (double)ss);
    }
}

// final layer: out = bn2(t2), plus mean-pool atomics
__global__ void bnapply_last(const float* __restrict__ t2, const float* __restrict__ bn_g,
                             const float* __restrict__ bn_b, const double* __restrict__ stats,
                             float* __restrict__ out, float* __restrict__ gsum,
                             float* __restrict__ gcnt, const int* __restrict__ batch) {
    __shared__ float ca[64], cb[64];
    int tid = threadIdx.x;
    if (tid < 64) {
        float mean = (float)(stats[tid] / NN);
        float var  = (float)(stats[64 + tid] / NN) - mean * mean;
        float a = bn_g[3 * 64 + tid] * rsqrtf(var + 1e-5f);
        ca[tid] = a;
        cb[tid] = bn_b[3 * 64 + tid] - mean * a;
    }
    __syncthreads();
    size_t base = (size_t)blockIdx.x * 4096;
    for (int it = 0; it < 16; it++) {
        size_t idx = base + it * 256 + tid;
        if (idx >= (size_t)NN * 64) return;
        int c = (int)(idx & 63);
        float v = ca[c] * t2[idx] + cb[c];
        out[idx] = v;
        int g = batch[idx >> 6];
        atomicAdd(&gsum[(size_t)g * 64 + c], v);
        if (c == 0) atomicAdd(&gcnt[g], 1.0f);
    }
}

__global__ void pool_div(const float* __restrict__ gsum, const float* __restrict__ gcnt,
                         float* __restrict__ out) {
    int id = blockIdx.x * 256 + threadIdx.x;   // NB*64
    int g = id >> 6;
    out[(size_t)NN * 64 + id] = gsum[id] / (gcnt[g] + 1e-9f);
}

extern "C" void kernel_launch(void* const* d_in, const int* in_sizes, int n_in,
                              void* d_out, int out_size, void* d_ws, size_t ws_size,
                              hipStream_t stream) {
    const float* atom_emb = (const float*)d_in[0];
    const float* bond_emb = (const float*)d_in[1];
    const float* eps      = (const float*)d_in[2];
    const float* W1       = (const float*)d_in[3];
    const float* b1       = (const float*)d_in[4];
    const float* bn1_g    = (const float*)d_in[5];
    const float* bn1_b    = (const float*)d_in[6];
    const float* W2       = (const float*)d_in[7];
    const float* b2       = (const float*)d_in[8];
    const float* bn2_g    = (const float*)d_in[9];
    const float* bn2_b    = (const float*)d_in[10];
    const int* x_feat     = (const int*)d_in[11];
    const int* edge_index = (const int*)d_in[12];
    const int* edge_attr  = (const int*)d_in[13];
    const int* batch      = (const int*)d_in[14];
    float* out = (float*)d_out;

    char* ws = (char*)d_ws;
    // ---- zero region (one memset) ----
    double* stats = (double*)ws;  ws += 2048 * 8;            // 8 slots x 256 doubles
    float* gsum   = (float*)ws;   ws += (size_t)NB * 64 * 4;
    float* gcnt   = (float*)ws;   ws += NB * 4;
    int* csr      = (int*)ws;     ws += (size_t)NN * 4;
    size_t zbytes = (size_t)(ws - (char*)d_ws);
    // ---- rest ----
    int* bsum       = (int*)ws;       ws += 128 * 4;
    unsigned* epack = (unsigned*)ws;  ws += (size_t)NE * 4;
    float* xbuf = (float*)ws;     ws += (size_t)NN * 64 * 4;   // h (layer 0) / t2 (layers>=1)
    float* agg  = (float*)ws;     ws += (size_t)NN * 64 * 4;
    unsigned short* w1h = (unsigned short*)ws; ws += 32768 * 2;
    unsigned short* w1l = (unsigned short*)ws; ws += 32768 * 2;
    unsigned short* w2h = (unsigned short*)ws; ws += 32768 * 2;
    unsigned short* w2l = (unsigned short*)ws; ws += 32768 * 2;

    hipMemsetAsync((void*)stats, 0, zbytes, stream);

    wcvt<<<256, 256, 0, stream>>>(W1, W2, w1h, w1l, w2h, w2l);
    deg_count<<<4883, 256, 0, stream>>>(edge_index, csr);
    scan_local<<<98, 256, 0, stream>>>(csr, bsum);
    scan_bsum<<<1, 128, 0, stream>>>(bsum);
    scan_add<<<98, 256, 0, stream>>>(csr, bsum);
    csr_fill<<<4883, 256, 0, stream>>>(edge_index, edge_attr, csr, epack);
    atom_encode<<<6250, 256, 0, stream>>>(atom_emb, x_feat, xbuf);

    for (int l = 0; l < 4; l++) {
        double* s1 = stats + (size_t)(l * 2) * 256;
        double* s2 = stats + (size_t)(l * 2 + 1) * 256;
        if (l == 0) {
            gather_k<false><<<6250, 256, 0, stream>>>(xbuf, bond_emb, eps, csr, epack, l,
                                                      nullptr, nullptr, nullptr, agg);
        } else {
            double* sp = stats + (size_t)((l - 1) * 2 + 1) * 256;
            gather_k<true><<<6250, 256, 0, stream>>>(xbuf, bond_emb, eps, csr, epack, l,
                                                     sp, bn2_g, bn2_b, agg);
        }
        mlp1stat<<<1563, 256, 0, stream>>>(agg, w1h, w1l, b1, l, s1);
        mlp_fused<<<1563, 256, 0, stream>>>(agg, w1h, w1l, b1, w2h, w2l, b2,
                                            bn1_g, bn1_b, s1, l, xbuf, s2);
    }
    bnapply_last<<<1563, 256, 0, stream>>>(xbuf, bn2_g, bn2_b,
                                           stats + (size_t)(3 * 2 + 1) * 256,
                                           out, gsum, gcnt, batch);
    pool_div<<<512, 256, 0, stream>>>(gsum, gcnt, out);
}